// Round 2
// baseline (100.068 us; speedup 1.0000x reference)
//
#include <hip/hip_runtime.h>

typedef float f32x4 __attribute__((ext_vector_type(4)));
typedef short s16x8 __attribute__((ext_vector_type(8)));
typedef unsigned short u16x8 __attribute__((ext_vector_type(8)));
typedef unsigned int u32;

// ---------- helpers ----------
__device__ __forceinline__ unsigned short f2bf(float f) {
  u32 x = __float_as_uint(f);
  u32 r = (x + 0x7fffu + ((x >> 16) & 1u)) >> 16;  // RNE
  return (unsigned short)r;
}

__device__ __forceinline__ void gload16(const void* g, void* lds) {
  __builtin_amdgcn_global_load_lds(
      (const __attribute__((address_space(1))) u32*)(uintptr_t)g,
      (__attribute__((address_space(3))) u32*)(u32)(uintptr_t)lds,
      16, 0, 0);
}

// ============================================================================
// Layout: A staged as "units" of 16 KiB = one (256-row x 32-k) k-half of a
// 256x64 K-tile, stored as the exact LDS image: byte o = r*64 + c_lds*16 + i,
// where the 16B chunk at (r, c_lds) holds k-chunk kq = c_lds ^ ((r>>1)&3)
// (bank-conflict-free swizzle for ds_read_b128; rule: swizzle source+read,
// keep global_load_lds dest linear). A unit index: (bm*16 + ks)*2 + kh.
// B identical with packed-n rows: n = (j>>4)<<6 | gate<<4 | (j&15)
// -> each wave's 4 n-frags = the 4 gates of one j  => lane-local epilogue.
// ============================================================================

__global__ __launch_bounds__(256) void pack_a_kernel(const float* __restrict__ X,
                                                     const float* __restrict__ C,
                                                     unsigned short* __restrict__ At) {
  int idx = blockIdx.x * 256 + threadIdx.x;  // 2,097,152 chunks of 16B
  int u = idx >> 10;                         // unit (2048)
  int co = idx & 1023;
  int r = co >> 2, cl = co & 3;
  int bm = u >> 5, ks = (u >> 1) & 15, kh = u & 1;
  int row = bm * 256 + r;
  int kq = cl ^ ((r >> 1) & 3);
  int k = ks * 64 + kh * 32 + kq * 8;
  const float* src = (k < 512) ? (X + (size_t)row * 512 + k)
                               : (C + (size_t)row * 512 + (k - 512));
  float4 v0 = *(const float4*)src;
  float4 v1 = *(const float4*)(src + 4);
  u16x8 h;
  h[0] = f2bf(v0.x); h[1] = f2bf(v0.y); h[2] = f2bf(v0.z); h[3] = f2bf(v0.w);
  h[4] = f2bf(v1.x); h[5] = f2bf(v1.y); h[6] = f2bf(v1.z); h[7] = f2bf(v1.w);
  *(u16x8*)((char*)At + (size_t)idx * 16) = h;
}

__global__ __launch_bounds__(256) void pack_b_kernel(
    const float* __restrict__ Wf, const float* __restrict__ Wi,
    const float* __restrict__ Wo, const float* __restrict__ Wc,
    const float* __restrict__ Uf, const float* __restrict__ Ui,
    const float* __restrict__ Uo, const float* __restrict__ Uc,
    unsigned short* __restrict__ Bt) {
  int idx = blockIdx.x * 256 + threadIdx.x;  // 262,144 chunks
  int u = idx >> 10;                         // unit (256)
  int co = idx & 1023;
  int r = co >> 2, cl = co & 3;
  int bn = u >> 5, ks = (u >> 1) & 15, kh = u & 1;
  int n = bn * 256 + r;
  int g = (n >> 4) & 3;
  int j = ((n >> 6) << 4) | (n & 15);
  int kq = cl ^ ((r >> 1) & 3);
  int k = ks * 64 + kh * 32 + kq * 8;
  const float* Wg = (g == 0) ? Wf : (g == 1) ? Wi : (g == 2) ? Wo : Wc;
  const float* Ug = (g == 0) ? Uf : (g == 1) ? Ui : (g == 2) ? Uo : Uc;
  const float* M = (k < 512) ? (Wg + (size_t)k * 512) : (Ug + (size_t)(k - 512) * 512);
  u16x8 h;
#pragma unroll
  for (int e = 0; e < 8; ++e) h[e] = f2bf(M[(size_t)e * 512 + j]);
  *(u16x8*)((char*)Bt + (size_t)idx * 16) = h;
}

// ============================================================================
// 256x256x(BK=64) 8-phase GEMM + fused LSTM epilogue.
// LDS: A: 4 slots (parity x khalf) x 16 KiB at 0; B: same at 65536. 128 KiB.
// Per tile t (4 phases q=(kh,mh)): stage rule
//   q0: A-kh1(t+1)  q1: B-kh1(t+1)  q2: A-kh0(t+2)  q3: B-kh0(t+2)
// (safe: slot's previous occupant last read the phase before; counts uniform
// via mod-16 wrap near the tail — re-stages stale-but-unread data.)
// vmcnt(8) at q1/q3 ends = 4 half-tiles in flight, never drained to 0.
// ============================================================================

#define BAR    asm volatile("s_barrier" ::: "memory")
#define WAITV8 asm volatile("s_waitcnt vmcnt(8)" ::: "memory")
#define LGKM0  do { asm volatile("s_waitcnt lgkmcnt(0)" ::: "memory"); \
                    __builtin_amdgcn_sched_barrier(0); } while (0)

#define STAGE_A(KS, KH, PDST)                                              \
  do { const char* s_ = gA + (((KS) * 2 + (KH)) << 14) + tid * 16;         \
       char* d_ = lds + (((PDST) * 2 + (KH)) << 14) + tid * 16;            \
       gload16(s_, d_); gload16(s_ + 8192, d_ + 8192); } while (0)
#define STAGE_B(KS, KH, PDST)                                              \
  do { const char* s_ = gB + (((KS) * 2 + (KH)) << 14) + tid * 16;         \
       char* d_ = lds + 65536 + (((PDST) * 2 + (KH)) << 14) + tid * 16;    \
       gload16(s_, d_); gload16(s_ + 8192, d_ + 8192); } while (0)

#define MFMA1(M, N) acc[M][N] = __builtin_amdgcn_mfma_f32_16x16x32_bf16(a##M##_, b##N##_, acc[M][N], 0, 0, 0)

#define PHASE(PAR, KH, MH, STAGE, WAITSTMT)                                          \
  do {                                                                               \
    const char* Ab_ = lds + (((PAR) * 2 + (KH)) << 14) + wr * 8192 + (MH) * 4096;    \
    const char* Bb_ = lds + 65536 + (((PAR) * 2 + (KH)) << 14) + wc * 4096;          \
    s16x8 a0_ = *(const s16x8*)(Ab_ + 0 * 1024 + lsw);                               \
    s16x8 a1_ = *(const s16x8*)(Ab_ + 1 * 1024 + lsw);                               \
    s16x8 a2_ = *(const s16x8*)(Ab_ + 2 * 1024 + lsw);                               \
    s16x8 a3_ = *(const s16x8*)(Ab_ + 3 * 1024 + lsw);                               \
    s16x8 b0_ = *(const s16x8*)(Bb_ + 0 * 1024 + lsw);                               \
    s16x8 b1_ = *(const s16x8*)(Bb_ + 1 * 1024 + lsw);                               \
    s16x8 b2_ = *(const s16x8*)(Bb_ + 2 * 1024 + lsw);                               \
    s16x8 b3_ = *(const s16x8*)(Bb_ + 3 * 1024 + lsw);                               \
    STAGE;                                                                           \
    WAITSTMT;                                                                        \
    BAR;                                                                             \
    LGKM0;                                                                           \
    __builtin_amdgcn_s_setprio(1);                                                   \
    { enum { M0 = (MH) * 4, M1 = M0 + 1, M2 = M0 + 2, M3 = M0 + 3 };                 \
      acc[M0][0] = __builtin_amdgcn_mfma_f32_16x16x32_bf16(a0_, b0_, acc[M0][0],0,0,0); \
      acc[M1][0] = __builtin_amdgcn_mfma_f32_16x16x32_bf16(a1_, b0_, acc[M1][0],0,0,0); \
      acc[M2][0] = __builtin_amdgcn_mfma_f32_16x16x32_bf16(a2_, b0_, acc[M2][0],0,0,0); \
      acc[M3][0] = __builtin_amdgcn_mfma_f32_16x16x32_bf16(a3_, b0_, acc[M3][0],0,0,0); \
      acc[M0][1] = __builtin_amdgcn_mfma_f32_16x16x32_bf16(a0_, b1_, acc[M0][1],0,0,0); \
      acc[M1][1] = __builtin_amdgcn_mfma_f32_16x16x32_bf16(a1_, b1_, acc[M1][1],0,0,0); \
      acc[M2][1] = __builtin_amdgcn_mfma_f32_16x16x32_bf16(a2_, b1_, acc[M2][1],0,0,0); \
      acc[M3][1] = __builtin_amdgcn_mfma_f32_16x16x32_bf16(a3_, b1_, acc[M3][1],0,0,0); \
      acc[M0][2] = __builtin_amdgcn_mfma_f32_16x16x32_bf16(a0_, b2_, acc[M0][2],0,0,0); \
      acc[M1][2] = __builtin_amdgcn_mfma_f32_16x16x32_bf16(a1_, b2_, acc[M1][2],0,0,0); \
      acc[M2][2] = __builtin_amdgcn_mfma_f32_16x16x32_bf16(a2_, b2_, acc[M2][2],0,0,0); \
      acc[M3][2] = __builtin_amdgcn_mfma_f32_16x16x32_bf16(a3_, b2_, acc[M3][2],0,0,0); \
      acc[M0][3] = __builtin_amdgcn_mfma_f32_16x16x32_bf16(a0_, b3_, acc[M0][3],0,0,0); \
      acc[M1][3] = __builtin_amdgcn_mfma_f32_16x16x32_bf16(a1_, b3_, acc[M1][3],0,0,0); \
      acc[M2][3] = __builtin_amdgcn_mfma_f32_16x16x32_bf16(a2_, b3_, acc[M2][3],0,0,0); \
      acc[M3][3] = __builtin_amdgcn_mfma_f32_16x16x32_bf16(a3_, b3_, acc[M3][3],0,0,0); \
    }                                                                                \
    __builtin_amdgcn_s_setprio(0);                                                   \
    __builtin_amdgcn_sched_barrier(0);                                               \
    BAR;                                                                             \
  } while (0)

__global__ __launch_bounds__(512, 2) void gemm_fused(
    const unsigned short* __restrict__ At_, const unsigned short* __restrict__ Bt_,
    const float* __restrict__ c_prev,
    const float* __restrict__ bf_, const float* __restrict__ bi_,
    const float* __restrict__ bo_, const float* __restrict__ bc_,
    float* __restrict__ H) {
  __shared__ __attribute__((aligned(128))) char lds[131072];
  int bid = blockIdx.x;
  int wg = (bid & 7) * 64 + (bid >> 3);  // XCD swizzle, 512 % 8 == 0 -> bijective
  int bn = wg & 7, bm = wg >> 3;
  int tid = threadIdx.x;
  int lane = tid & 63, w = tid >> 6;
  int wr = w >> 2, wc = w & 3;           // 2 x 4 waves
  int l15 = lane & 15, kq = lane >> 4;
  int lsw = l15 * 64 + ((kq ^ ((l15 >> 1) & 3)) << 4);  // per-lane swizzled offset

  const char* gA = (const char*)At_ + (size_t)bm * (32 * 16384);
  const char* gB = (const char*)Bt_ + (size_t)bn * (32 * 16384);

  f32x4 acc[8][4] = {};

  // prologue: tile0 (all 4 halves) + tile1 k-half0
  STAGE_A(0, 0, 0); STAGE_B(0, 0, 0);
  STAGE_A(0, 1, 0); STAGE_B(0, 1, 0);
  STAGE_A(1, 0, 1); STAGE_B(1, 0, 1);
  WAITV8;  // first two units (tile0 kh0) resident
  BAR;

  for (int t = 0; t < 16; t += 2) {
    int p1 = (t + 1) & 15, p2 = (t + 2) & 15, p3 = (t + 3) & 15;
    // tile t (parity 0)
    PHASE(0, 0, 0, STAGE_A(p1, 1, 1), );
    PHASE(0, 0, 1, STAGE_B(p1, 1, 1), WAITV8);
    PHASE(0, 1, 0, STAGE_A(p2, 0, 0), );
    PHASE(0, 1, 1, STAGE_B(p2, 0, 0), WAITV8);
    // tile t+1 (parity 1)
    PHASE(1, 0, 0, STAGE_A(p2, 1, 0), );
    PHASE(1, 0, 1, STAGE_B(p2, 1, 0), WAITV8);
    PHASE(1, 1, 0, STAGE_A(p3, 0, 1), );
    PHASE(1, 1, 1, STAGE_B(p3, 0, 1), WAITV8);
  }

  // ---------------- epilogue: lane-local LSTM gates ----------------
  int j = (bn * 4 + wc) * 16 + l15;
  float vbf = bf_[j], vbi = bi_[j], vbo = bo_[j], vbc = bc_[j];
  int row0 = bm * 256 + wr * 128 + kq * 4;
#pragma unroll
  for (int m = 0; m < 8; ++m) {
#pragma unroll
    for (int ri = 0; ri < 4; ++ri) {
      int row = row0 + m * 16 + ri;
      float fp = acc[m][0][ri] + vbf;
      float ip = acc[m][1][ri] + vbi;
      float op = acc[m][2][ri] + vbo;
      float cq = acc[m][3][ri] + vbc;
      float ft = 1.0f / (1.0f + __expf(-fp));
      float it = 1.0f / (1.0f + __expf(-ip));
      float ot = 1.0f / (1.0f + __expf(-op));
      float ch = 1.0f - 2.0f / (1.0f + __expf(2.0f * cq));
      float cp = c_prev[(size_t)row * 512 + j];
      float ct = ft * cp + it * ch;
      float th = 1.0f - 2.0f / (1.0f + __expf(2.0f * ct));
      H[(size_t)row * 512 + j] = ot * th;
    }
  }
}

extern "C" void kernel_launch(void* const* d_in, const int* in_sizes, int n_in,
                              void* d_out, int out_size, void* d_ws, size_t ws_size,
                              hipStream_t stream) {
  const float* X = (const float*)d_in[0];
  const float* Cp = (const float*)d_in[1];
  const float* Wf = (const float*)d_in[2];
  const float* Wi = (const float*)d_in[3];
  const float* Wo = (const float*)d_in[4];
  const float* Wc = (const float*)d_in[5];
  const float* Uf = (const float*)d_in[6];
  const float* Ui = (const float*)d_in[7];
  const float* Uo = (const float*)d_in[8];
  const float* Uc = (const float*)d_in[9];
  const float* bfp = (const float*)d_in[10];
  const float* bip = (const float*)d_in[11];
  const float* bop = (const float*)d_in[12];
  const float* bcp = (const float*)d_in[13];
  float* H = (float*)d_out;

  unsigned short* At = (unsigned short*)d_ws;                       // 32 MiB
  unsigned short* Bt = (unsigned short*)((char*)d_ws + 33554432u);  //  4 MiB

  pack_a_kernel<<<8192, 256, 0, stream>>>(X, Cp, At);
  pack_b_kernel<<<1024, 256, 0, stream>>>(Wf, Wi, Wo, Wc, Uf, Ui, Uo, Uc, Bt);
  gemm_fused<<<512, 512, 0, stream>>>(At, Bt, Cp, bfp, bip, bop, bcp, H);
}

// Round 4
// 97.347 us; speedup vs baseline: 1.0279x; 1.0279x over previous
//
#include <hip/hip_runtime.h>

typedef float f32x4 __attribute__((ext_vector_type(4)));
typedef short s16x8 __attribute__((ext_vector_type(8)));
typedef unsigned short u16x8 __attribute__((ext_vector_type(8)));
typedef unsigned int u32;

// ---------- helpers ----------
__device__ __forceinline__ unsigned short f2bf(float f) {
  u32 x = __float_as_uint(f);
  u32 r = (x + 0x7fffu + ((x >> 16) & 1u)) >> 16;  // RNE
  return (unsigned short)r;
}

__device__ __forceinline__ void gload16(const void* g, void* lds) {
  __builtin_amdgcn_global_load_lds(
      (const __attribute__((address_space(1))) u32*)(uintptr_t)g,
      (__attribute__((address_space(3))) u32*)(u32)(uintptr_t)lds,
      16, 0, 0);
}

// ============================================================================
// A staged as 16 KiB "units" = one (256-row x 32-k) k-half of a 256x64 K-tile,
// stored as the exact LDS image: byte o = r*64 + c_lds*16, chunk at (r,c_lds)
// holds k-chunk kq = c_lds ^ ((r>>1)&3) (conflict-free for ds_read_b128; dest
// of global_load_lds stays linear, source is pre-swizzled). Unit index:
// (bm*16 + ks)*2 + kh.  B identical with packed-n rows:
// n = (j>>4)<<6 | gate<<4 | (j&15)  -> a wave's 4 n-frags = 4 gates of one j
// => lane-local LSTM epilogue.
// ============================================================================

__global__ __launch_bounds__(256) void pack_a_kernel(const float* __restrict__ X,
                                                     const float* __restrict__ C,
                                                     unsigned short* __restrict__ At) {
  int idx = blockIdx.x * 256 + threadIdx.x;  // 2,097,152 chunks of 16B
  int u = idx >> 10;
  int co = idx & 1023;
  int r = co >> 2, cl = co & 3;
  int bm = u >> 5, ks = (u >> 1) & 15, kh = u & 1;
  int row = bm * 256 + r;
  int kq = cl ^ ((r >> 1) & 3);
  int k = ks * 64 + kh * 32 + kq * 8;
  const float* src = (k < 512) ? (X + (size_t)row * 512 + k)
                               : (C + (size_t)row * 512 + (k - 512));
  float4 v0 = *(const float4*)src;
  float4 v1 = *(const float4*)(src + 4);
  u16x8 h;
  h[0] = f2bf(v0.x); h[1] = f2bf(v0.y); h[2] = f2bf(v0.z); h[3] = f2bf(v0.w);
  h[4] = f2bf(v1.x); h[5] = f2bf(v1.y); h[6] = f2bf(v1.z); h[7] = f2bf(v1.w);
  *(u16x8*)((char*)At + (size_t)idx * 16) = h;
}

__global__ __launch_bounds__(256) void pack_b_kernel(
    const float* __restrict__ Wf, const float* __restrict__ Wi,
    const float* __restrict__ Wo, const float* __restrict__ Wc,
    const float* __restrict__ Uf, const float* __restrict__ Ui,
    const float* __restrict__ Uo, const float* __restrict__ Uc,
    unsigned short* __restrict__ Bt) {
  int idx = blockIdx.x * 256 + threadIdx.x;  // 262,144 chunks
  int u = idx >> 10;
  int co = idx & 1023;
  int r = co >> 2, cl = co & 3;
  int bn = u >> 5, ks = (u >> 1) & 15, kh = u & 1;
  int n = bn * 256 + r;
  int g = (n >> 4) & 3;
  int j = ((n >> 6) << 4) | (n & 15);
  int kq = cl ^ ((r >> 1) & 3);
  int k = ks * 64 + kh * 32 + kq * 8;
  const float* Wg = (g == 0) ? Wf : (g == 1) ? Wi : (g == 2) ? Wo : Wc;
  const float* Ug = (g == 0) ? Uf : (g == 1) ? Ui : (g == 2) ? Uo : Uc;
  const float* M = (k < 512) ? (Wg + (size_t)k * 512) : (Ug + (size_t)(k - 512) * 512);
  u16x8 h;
#pragma unroll
  for (int e = 0; e < 8; ++e) h[e] = f2bf(M[(size_t)e * 512 + j]);
  *(u16x8*)((char*)Bt + (size_t)idx * 16) = h;
}

// ============================================================================
// 256x256x(BK=64) 8-phase GEMM + fused LSTM epilogue.
// LDS: A: 4 slots (parity x khalf) x 16 KiB at 0; B same at 65536. 128 KiB.
// Phases per tile: q0=(kh0,mh0: reads A+B), q1=(kh0,mh1: reads A only, B held
// in regs), q2=(kh1,mh0), q3=(kh1,mh1). Stage rule per tile t:
//   q0: A-kh1(t+1)  q1: B-kh1(t+1)  q2: A-kh0(t+2)  q3: B-kh0(t+2)
// PROLOGUE stages 6 units (A+B of tile0 kh0/kh1, A+B of tile1 kh0): the
// loop's first iteration consumes tile1-kh0 at q4/q5 BEFORE any loop stage of
// it can land (round-3 bug: B(1,kh0) was missing -> garbage K=64..95).
// vmcnt(8) in prologue retires exactly tile0-kh0 A+B. vmcnt(6) at q1/q3 in
// the loop: with the 12-load prologue, stages through phase P-4 are retired
// at phase P's wait; all consumers read stages from >=5 phases earlier, after
// a barrier that follows the wait. lgkm waits before MFMA are COMPILER-
// inserted (plain loads); one lgkmcnt(0) at phase end (free by then) orders
// slot-restage after pending reads.
// ============================================================================

#define BAR    asm volatile("s_barrier" ::: "memory")
#define WAITV8 asm volatile("s_waitcnt vmcnt(8)" ::: "memory")
#define WAITV6 asm volatile("s_waitcnt vmcnt(6)" ::: "memory")
#define LG0    asm volatile("s_waitcnt lgkmcnt(0)" ::: "memory")

#define STAGE_A(KS, KH, PDST)                                              \
  do { const char* s_ = gA + (((KS) * 2 + (KH)) << 14) + tid * 16;         \
       char* d_ = lds + (((PDST) * 2 + (KH)) << 14) + tid * 16;            \
       gload16(s_, d_); gload16(s_ + 8192, d_ + 8192); } while (0)
#define STAGE_B(KS, KH, PDST)                                              \
  do { const char* s_ = gB + (((KS) * 2 + (KH)) << 14) + tid * 16;         \
       char* d_ = lds + 65536 + (((PDST) * 2 + (KH)) << 14) + tid * 16;    \
       gload16(s_, d_); gload16(s_ + 8192, d_ + 8192); } while (0)

#define MFMA16(M0)                                                                      \
  do {                                                                                  \
    acc[(M0)+0][0] = __builtin_amdgcn_mfma_f32_16x16x32_bf16(a0_, vb0, acc[(M0)+0][0],0,0,0); \
    acc[(M0)+1][0] = __builtin_amdgcn_mfma_f32_16x16x32_bf16(a1_, vb0, acc[(M0)+1][0],0,0,0); \
    acc[(M0)+2][0] = __builtin_amdgcn_mfma_f32_16x16x32_bf16(a2_, vb0, acc[(M0)+2][0],0,0,0); \
    acc[(M0)+3][0] = __builtin_amdgcn_mfma_f32_16x16x32_bf16(a3_, vb0, acc[(M0)+3][0],0,0,0); \
    acc[(M0)+0][1] = __builtin_amdgcn_mfma_f32_16x16x32_bf16(a0_, vb1, acc[(M0)+0][1],0,0,0); \
    acc[(M0)+1][1] = __builtin_amdgcn_mfma_f32_16x16x32_bf16(a1_, vb1, acc[(M0)+1][1],0,0,0); \
    acc[(M0)+2][1] = __builtin_amdgcn_mfma_f32_16x16x32_bf16(a2_, vb1, acc[(M0)+2][1],0,0,0); \
    acc[(M0)+3][1] = __builtin_amdgcn_mfma_f32_16x16x32_bf16(a3_, vb1, acc[(M0)+3][1],0,0,0); \
    acc[(M0)+0][2] = __builtin_amdgcn_mfma_f32_16x16x32_bf16(a0_, vb2, acc[(M0)+0][2],0,0,0); \
    acc[(M0)+1][2] = __builtin_amdgcn_mfma_f32_16x16x32_bf16(a1_, vb2, acc[(M0)+1][2],0,0,0); \
    acc[(M0)+2][2] = __builtin_amdgcn_mfma_f32_16x16x32_bf16(a2_, vb2, acc[(M0)+2][2],0,0,0); \
    acc[(M0)+3][2] = __builtin_amdgcn_mfma_f32_16x16x32_bf16(a3_, vb2, acc[(M0)+3][2],0,0,0); \
    acc[(M0)+0][3] = __builtin_amdgcn_mfma_f32_16x16x32_bf16(a0_, vb3, acc[(M0)+0][3],0,0,0); \
    acc[(M0)+1][3] = __builtin_amdgcn_mfma_f32_16x16x32_bf16(a1_, vb3, acc[(M0)+1][3],0,0,0); \
    acc[(M0)+2][3] = __builtin_amdgcn_mfma_f32_16x16x32_bf16(a2_, vb3, acc[(M0)+2][3],0,0,0); \
    acc[(M0)+3][3] = __builtin_amdgcn_mfma_f32_16x16x32_bf16(a3_, vb3, acc[(M0)+3][3],0,0,0); \
  } while (0)

// mh0 phase: load 4 A-frags + 4 B-frags (B persists into the mh1 phase)
#define PH_MH0(PAR, KH, STAGE, WAITSTMT)                                             \
  do {                                                                               \
    const char* Ab_ = lds + (((PAR) * 2 + (KH)) << 14) + wr * 8192;                  \
    const char* Bb_ = lds + 65536 + (((PAR) * 2 + (KH)) << 14) + wc * 4096;          \
    s16x8 a0_ = *(const s16x8*)(Ab_ + 0 * 1024 + lsw);                               \
    s16x8 a1_ = *(const s16x8*)(Ab_ + 1 * 1024 + lsw);                               \
    s16x8 a2_ = *(const s16x8*)(Ab_ + 2 * 1024 + lsw);                               \
    s16x8 a3_ = *(const s16x8*)(Ab_ + 3 * 1024 + lsw);                               \
    vb0 = *(const s16x8*)(Bb_ + 0 * 1024 + lsw);                                     \
    vb1 = *(const s16x8*)(Bb_ + 1 * 1024 + lsw);                                     \
    vb2 = *(const s16x8*)(Bb_ + 2 * 1024 + lsw);                                     \
    vb3 = *(const s16x8*)(Bb_ + 3 * 1024 + lsw);                                     \
    STAGE;                                                                           \
    WAITSTMT;                                                                        \
    BAR;                                                                             \
    __builtin_amdgcn_s_setprio(1);                                                   \
    MFMA16(0);                                                                       \
    __builtin_amdgcn_s_setprio(0);                                                   \
    LG0;                                                                             \
    BAR;                                                                             \
  } while (0)

// mh1 phase: load 4 A-frags only; B-frags held in vb0..vb3
#define PH_MH1(PAR, KH, STAGE, WAITSTMT)                                             \
  do {                                                                               \
    const char* Ab_ = lds + (((PAR) * 2 + (KH)) << 14) + wr * 8192 + 4096;           \
    s16x8 a0_ = *(const s16x8*)(Ab_ + 0 * 1024 + lsw);                               \
    s16x8 a1_ = *(const s16x8*)(Ab_ + 1 * 1024 + lsw);                               \
    s16x8 a2_ = *(const s16x8*)(Ab_ + 2 * 1024 + lsw);                               \
    s16x8 a3_ = *(const s16x8*)(Ab_ + 3 * 1024 + lsw);                               \
    STAGE;                                                                           \
    WAITSTMT;                                                                        \
    BAR;                                                                             \
    __builtin_amdgcn_s_setprio(1);                                                   \
    MFMA16(4);                                                                       \
    __builtin_amdgcn_s_setprio(0);                                                   \
    LG0;                                                                             \
    BAR;                                                                             \
  } while (0)

__global__ __launch_bounds__(512, 2) void gemm_fused(
    const unsigned short* __restrict__ At_, const unsigned short* __restrict__ Bt_,
    const float* __restrict__ c_prev,
    const float* __restrict__ bf_, const float* __restrict__ bi_,
    const float* __restrict__ bo_, const float* __restrict__ bc_,
    float* __restrict__ H) {
  __shared__ __attribute__((aligned(128))) char lds[131072];
  int bid = blockIdx.x;
  int wg = (bid & 7) * 64 + (bid >> 3);  // XCD swizzle, 512 % 8 == 0 -> bijective
  int bn = wg & 7, bm = wg >> 3;
  int tid = threadIdx.x;
  int lane = tid & 63, w = tid >> 6;
  int wr = w >> 2, wc = w & 3;           // 2 x 4 waves
  int l15 = lane & 15, kq = lane >> 4;
  int lsw = l15 * 64 + ((kq ^ ((l15 >> 1) & 3)) << 4);  // per-lane swizzled offset

  const char* gA = (const char*)At_ + (size_t)bm * (32 * 16384);
  const char* gB = (const char*)Bt_ + (size_t)bn * (32 * 16384);

  f32x4 acc[8][4] = {};
  s16x8 vb0, vb1, vb2, vb3;

  // prologue: tile0 (both k-halves, A+B) + tile1 k-half0 (A+B) = 6 units
  STAGE_A(0, 0, 0); STAGE_B(0, 0, 0);
  STAGE_A(0, 1, 0); STAGE_B(0, 1, 0);
  STAGE_A(1, 0, 1); STAGE_B(1, 0, 1);
  WAITV8;  // 12 issued, <=8 outstanding -> tile0 kh0 (A+B) resident
  BAR;

  for (int t = 0; t < 16; t += 2) {
    int p1 = (t + 1) & 15, p2 = (t + 2) & 15, p3 = (t + 3) & 15;
    // tile t (parity 0)
    PH_MH0(0, 0, STAGE_A(p1, 1, 1), );
    PH_MH1(0, 0, STAGE_B(p1, 1, 1), WAITV6);
    PH_MH0(0, 1, STAGE_A(p2, 0, 0), );
    PH_MH1(0, 1, STAGE_B(p2, 0, 0), WAITV6);
    // tile t+1 (parity 1)
    PH_MH0(1, 0, STAGE_A(p2, 1, 0), );
    PH_MH1(1, 0, STAGE_B(p2, 1, 0), WAITV6);
    PH_MH0(1, 1, STAGE_A(p3, 0, 1), );
    PH_MH1(1, 1, STAGE_B(p3, 0, 1), WAITV6);
  }

  // ---------------- epilogue: lane-local LSTM gates ----------------
  int j = (bn * 4 + wc) * 16 + l15;
  float vbf = bf_[j], vbi = bi_[j], vbo = bo_[j], vbc = bc_[j];
  int row0 = bm * 256 + wr * 128 + kq * 4;
#pragma unroll
  for (int m = 0; m < 8; ++m) {
#pragma unroll
    for (int ri = 0; ri < 4; ++ri) {
      int row = row0 + m * 16 + ri;
      float fp = acc[m][0][ri] + vbf;
      float ip = acc[m][1][ri] + vbi;
      float op = acc[m][2][ri] + vbo;
      float cq = acc[m][3][ri] + vbc;
      float ft = 1.0f / (1.0f + __expf(-fp));
      float it = 1.0f / (1.0f + __expf(-ip));
      float ot = 1.0f / (1.0f + __expf(-op));
      float ch = 1.0f - 2.0f / (1.0f + __expf(2.0f * cq));
      float cp = c_prev[(size_t)row * 512 + j];
      float ct = ft * cp + it * ch;
      float th = 1.0f - 2.0f / (1.0f + __expf(2.0f * ct));
      H[(size_t)row * 512 + j] = ot * th;
    }
  }
}

extern "C" void kernel_launch(void* const* d_in, const int* in_sizes, int n_in,
                              void* d_out, int out_size, void* d_ws, size_t ws_size,
                              hipStream_t stream) {
  const float* X = (const float*)d_in[0];
  const float* Cp = (const float*)d_in[1];
  const float* Wf = (const float*)d_in[2];
  const float* Wi = (const float*)d_in[3];
  const float* Wo = (const float*)d_in[4];
  const float* Wc = (const float*)d_in[5];
  const float* Uf = (const float*)d_in[6];
  const float* Ui = (const float*)d_in[7];
  const float* Uo = (const float*)d_in[8];
  const float* Uc = (const float*)d_in[9];
  const float* bfp = (const float*)d_in[10];
  const float* bip = (const float*)d_in[11];
  const float* bop = (const float*)d_in[12];
  const float* bcp = (const float*)d_in[13];
  float* H = (float*)d_out;

  unsigned short* At = (unsigned short*)d_ws;                       // 32 MiB
  unsigned short* Bt = (unsigned short*)((char*)d_ws + 33554432u);  //  4 MiB

  pack_a_kernel<<<8192, 256, 0, stream>>>(X, Cp, At);
  pack_b_kernel<<<1024, 256, 0, stream>>>(Wf, Wi, Wo, Wc, Uf, Ui, Uo, Uc, Bt);
  gemm_fused<<<512, 512, 0, stream>>>(At, Bt, Cp, bfp, bip, bop, bcp, H);
}